// Round 3
// baseline (560.539 us; speedup 1.0000x reference)
//
#include <hip/hip_runtime.h>

// SSIM loss via separable 11-tap Gaussian, both conv passes on matrix cores
// (v_mfma_f32_16x16x32_f16). R13 = R12 + width-maximal LDS geometry + fused
// final reduction. R12 was VALU/LDS-issue bound (VALU 49%, HBM 11%, Mfma 6%,
// bank-conflict 3.19M): odd strides forced 2xb64/4xb32 LDS ops and a
// div-by-22 staging loop.
// Geometry (the whole trick): x0 = 32bx-8 (48 staged cols), y0 = 64by-9
// (80 staged rows).
//  - Phase A: pure float4 -> cvt_pk -> ds_write_b64; 960 items, addressing
//    by /12 (cheap magic mul); linear LDS dest.
//  - sx/sy: f16 col-pair packed, 80 rows x 24 words; row 16B-aligned ->
//    phase B A-operand = ONE ds_read_b128 (uniform banks, zero conflict).
//  - Phase B: out col n needs staged [n+3,n+13]; both 16-col tiles read at
//    sbase offset 8*tl and share ONE tap fragment t = k-lm-3. Bands exactly
//    {0,16,32,48,64} (80 rows, no overlap hack). k outside [lm+3,lm+13]
//    hits the zero tap sentinel; all staged data is written, so no NaN risk.
//  - hq COLUMN-major [2 slots][32 cols][40 rp]: B stores ds_write_b64
//    (contiguous row-pairs rp=8b+2lg), C reads ds_read_b128 (rp=8wv+4lg,
//    16B aligned for ALL waves since rpb=8wv uniformly; taps t = k-lm-4,
//    no wave-3 special case). All patterns bank-uniform.
//  - 3-chunk quantity loop over 2-slot hq kept from R12 (occupancy).
//  - Fused reduction: ws counter (hipMemsetAsync'd to 0 each launch),
//    last block (device-scope atomicAdd) sums partials via agent-scope
//    atomic loads (bypass stale per-XCD L2) -> out[0]. ssim_reduce removed.
// LDS 25.7KB -> 6 blocks/CU (R12's 7-block cap wasn't binding: 19 waves
// measured < 28 cap).

typedef __fp16 f16x8 __attribute__((ext_vector_type(8)));
typedef float f32x4 __attribute__((ext_vector_type(4)));
typedef unsigned u32x4 __attribute__((ext_vector_type(4)));

__device__ __forceinline__ unsigned pk2(float a, float b) {
    return __builtin_bit_cast(unsigned, __builtin_amdgcn_cvt_pkrtz(a, b));
}
__device__ __forceinline__ f32x4 mfma16(f16x8 a, f16x8 b, f32x4 c) {
    return __builtin_amdgcn_mfma_f32_16x16x32_f16(a, b, c, 0, 0, 0);
}

#define SXW 24   // staged words/row (48 f16 cols), rows 16B-aligned
#define HRP 40   // hq row-pairs per column (80 staged rows)

__global__ __launch_bounds__(256, 6) void ssim_main(
    const float* __restrict__ xg, const float* __restrict__ yg,
    const float* __restrict__ w2d, float* __restrict__ part,
    unsigned* __restrict__ cnt, float* __restrict__ out,
    int nblk, float invN)
{
    __shared__ __align__(16) unsigned sx[80 * SXW];      // 7680 B
    __shared__ __align__(16) unsigned sy[80 * SXW];      // 7680 B
    __shared__ __align__(16) unsigned hq[2][32 * HRP];   // 10240 B
    __shared__ float gsf[12];
    __shared__ float wred[4];
    __shared__ int isLast;

    const int tid = threadIdx.x;

    // 1D kernel = row sums of the 2D window (outer(g,g), sum 1).
    // gsf[11] = 0 sentinel for the clamped tap lookup.
    if (tid < 12) {
        float s = 0.0f;
        if (tid < 11) {
            #pragma unroll
            for (int j = 0; j < 11; ++j) s += w2d[tid * 11 + j];
        }
        gsf[tid] = s;
    }

    // XCD-aware bijective swizzle (nwg = 128*Z, %8==0).
    const int nwg = 128 * (int)gridDim.z;
    const int flat = (int)blockIdx.x + 16 * ((int)blockIdx.y + 8 * (int)blockIdx.z);
    const int swz = (flat & 7) * (nwg >> 3) + (flat >> 3);
    const int bx = swz & 15, by = (swz >> 4) & 7, bz = swz >> 7;

    const int x0 = bx * 32 - 8;   // mult of 4 -> float4-aligned
    const int y0 = by * 64 - 9;
    const size_t zoff = (size_t)bz * (512 * 512);
    const float* __restrict__ xp = xg + zoff;
    const float* __restrict__ yp = yg + zoff;

    // Phase A: stage 80 rows x 12 float4-groups, zero-padded at edges.
    const bool interior = (x0 >= 0) & (x0 + 47 < 512) & (y0 >= 0) & (y0 + 79 < 512);
    if (interior) {
        for (int it = tid; it < 80 * 12; it += 256) {
            const int r = it / 12, c4 = it - r * 12;
            const int o = (y0 + r) * 512 + x0 + 4 * c4;
            const float4 vx = *(const float4*)&xp[o];
            const float4 vy = *(const float4*)&yp[o];
            *(uint2*)&sx[2 * it] = make_uint2(pk2(vx.x, vx.y), pk2(vx.z, vx.w));
            *(uint2*)&sy[2 * it] = make_uint2(pk2(vy.x, vy.y), pk2(vy.z, vy.w));
        }
    } else {
        for (int it = tid; it < 80 * 12; it += 256) {
            const int r = it / 12, c4 = it - r * 12;
            const int gr = y0 + r, gc0 = x0 + 4 * c4;
            const bool rok = (unsigned)gr < 512u;
            float xv[4], yv[4];
            #pragma unroll
            for (int j = 0; j < 4; ++j) {
                const int gc = gc0 + j;
                const bool ok = rok & ((unsigned)gc < 512u);
                const int o = gr * 512 + gc;
                xv[j] = ok ? xp[o] : 0.f;
                yv[j] = ok ? yp[o] : 0.f;
            }
            *(uint2*)&sx[2 * it] = make_uint2(pk2(xv[0], xv[1]), pk2(xv[2], xv[3]));
            *(uint2*)&sy[2 * it] = make_uint2(pk2(yv[0], yv[1]), pk2(yv[2], yv[3]));
        }
    }
    __syncthreads();

    const int lane = tid & 63, wv = tid >> 6;
    const int lm = lane & 15, lg = lane >> 4;

    // f16 taps with center correction (f16 tap sum ~= 1). Clamped dynamic
    // LDS index (register array + runtime index would go to scratch).
    float ssum = 0.0f;
    #pragma unroll
    for (int k = 0; k < 11; ++k)
        if (k != 5) ssum += (float)(__fp16)gsf[k];
    const __fp16 cc = (__fp16)(1.0f - ssum);
    auto tap = [&](int t) -> __fp16 {
        const unsigned u = ((unsigned)t <= 11u) ? (unsigned)t : 11u;  // ->0
        const __fp16 hv = (__fp16)gsf[u];
        return (t == 5) ? cc : hv;
    };

    // Tap fragments (k = 8*lg + e):
    //  Phase B (B operand, both tiles): t = k - lm - 3
    //  Phase C (A operand, all waves):  t = k - lm - 4
    f16x8 bt, afr;
    #pragma unroll
    for (int e = 0; e < 8; ++e) {
        const int k = 8 * lg + e;
        bt[e]  = tap(k - lm - 3);
        afr[e] = tap(k - lm - 4);
    }

    f32x4 acc[2][5];
    #pragma unroll
    for (int ch = 0; ch < 2; ++ch)
        #pragma unroll
        for (int q = 0; q < 5; ++q)
            acc[ch][q] = (f32x4){0.f, 0.f, 0.f, 0.f};

    const int rpb = 8 * wv;   // hq rp base of the C-phase K window (uniform!)

    // Chunks over quantities: {x,y} -> {x*x,y*y} -> {x*y}, reusing hq[0..1].
    #pragma unroll
    for (int chunk = 0; chunk < 3; ++chunk) {
        // Phase B: horizontal conv as MFMA. 10 items = (band b, col-tile tl);
        // band staged rows 16b..16b+15, b = 0..4.
        for (int i = wv; i < 10; i += 4) {
            const int b = i >> 1, tl = i & 1;
            const int sbase = (16 * b + lm) * SXW + 8 * tl + 4 * lg;
            const f16x8 xa = __builtin_bit_cast(f16x8, *(const u32x4*)&sx[sbase]);
            const f16x8 ya = __builtin_bit_cast(f16x8, *(const u32x4*)&sy[sbase]);
            const f32x4 z4 = {0.f, 0.f, 0.f, 0.f};
            f32x4 d0 = z4, d1 = z4;
            if (chunk == 0)      { d0 = mfma16(xa, bt, z4);      d1 = mfma16(ya, bt, z4); }
            else if (chunk == 1) { d0 = mfma16(xa * xa, bt, z4); d1 = mfma16(ya * ya, bt, z4); }
            else                 { d0 = mfma16(xa * ya, bt, z4); }
            // D: col = lm (+16*tl), staged rows 16b + 4lg + {0..3}
            //  -> rp = 8b + 2lg, 8b + 2lg + 1: contiguous in col-major hq.
            const int ob = (16 * tl + lm) * HRP + 8 * b + 2 * lg;
            *(uint2*)&hq[0][ob] = make_uint2(pk2(d0[0], d0[1]), pk2(d0[2], d0[3]));
            if (chunk < 2)
                *(uint2*)&hq[1][ob] = make_uint2(pk2(d1[0], d1[1]), pk2(d1[2], d1[3]));
        }
        __syncthreads();

        // Phase C: vertical conv as MFMA into the chunk's accumulators.
        #pragma unroll
        for (int ch = 0; ch < 2; ++ch) {
            const int cb = (16 * ch + lm) * HRP + rpb + 4 * lg;  // 16B aligned
            #pragma unroll
            for (int s = 0; s < 2; ++s) {
                if (chunk == 2 && s == 1) continue;
                const u32x4 w4 = *(const u32x4*)&hq[s][cb];
                acc[ch][2 * chunk + s] =
                    mfma16(afr, __builtin_bit_cast(f16x8, w4), acc[ch][2 * chunk + s]);
            }
        }
        if (chunk < 2) __syncthreads();   // hq reads done before next B rewrites
    }

    // SSIM epilogue: lane holds out col 16ch+lm, out rows 16wv+4lg+{0..3}.
    float lsum = 0.0f;
    const float C1 = 1e-4f, C2 = 9e-4f;
    #pragma unroll
    for (int ch = 0; ch < 2; ++ch) {
        #pragma unroll
        for (int r = 0; r < 4; ++r) {
            const float mx = acc[ch][0][r], my = acc[ch][1][r];
            const float exx = acc[ch][2][r], eyy = acc[ch][3][r];
            const float exy = acc[ch][4][r];
            const float mx2 = mx * mx, my2 = my * my, mxy = mx * my;
            const float vx = exx - mx2, vy = eyy - my2, vxy = exy - mxy;
            const float num = (2.0f * mxy + C1) * (2.0f * vxy + C2);
            const float den = (mx2 + my2 + C1) * (vx + vy + C2) + 1e-12f;
            lsum = fmaf(num, __builtin_amdgcn_rcpf(den), lsum);
        }
    }

    // Wave reduce -> cross-wave via LDS -> per-block partial; last-arriving
    // block does the grid reduction (counter was memset to 0 this launch).
    #pragma unroll
    for (int off = 32; off > 0; off >>= 1)
        lsum += __shfl_down(lsum, off, 64);
    if ((tid & 63) == 0) wred[tid >> 6] = lsum;
    __syncthreads();
    if (tid == 0) {
        const float total = wred[0] + wred[1] + wred[2] + wred[3];
        __hip_atomic_store(&part[swz], total, __ATOMIC_RELEASE,
                           __HIP_MEMORY_SCOPE_AGENT);
        __threadfence();
        const unsigned old = __hip_atomic_fetch_add(cnt, 1u, __ATOMIC_ACQ_REL,
                                                    __HIP_MEMORY_SCOPE_AGENT);
        isLast = (old == (unsigned)(nblk - 1));
    }
    __syncthreads();
    if (isLast) {
        float s = 0.0f;
        for (int i = tid; i < nblk; i += 256)
            s += __hip_atomic_load(&part[i], __ATOMIC_RELAXED,
                                   __HIP_MEMORY_SCOPE_AGENT);
        #pragma unroll
        for (int off = 32; off > 0; off >>= 1)
            s += __shfl_down(s, off, 64);
        if ((tid & 63) == 0) wred[tid >> 6] = s;
        __syncthreads();
        if (tid == 0)
            out[0] = 1.0f - (wred[0] + wred[1] + wred[2] + wred[3]) * invN;
    }
}

extern "C" void kernel_launch(void* const* d_in, const int* in_sizes, int n_in,
                              void* d_out, int out_size, void* d_ws, size_t ws_size,
                              hipStream_t stream) {
    const float* x   = (const float*)d_in[0];
    const float* y   = (const float*)d_in[1];
    const float* w2d = (const float*)d_in[2];  // (3,1,11,11); channels identical
    float* out  = (float*)d_out;
    float* part = (float*)d_ws;                // 6144 floats = 24 KB
    unsigned* cnt = (unsigned*)((char*)d_ws + 6144 * sizeof(float));

    const int H = 512, W = 512;
    const int total = in_sizes[0];              // 16*3*512*512
    const int Z = total / (H * W);              // 48

    dim3 grid(W / 32, H / 64, Z);               // 16 x 8 x 48 = 6144 blocks
    const int nblk = (W / 32) * (H / 64) * Z;
    const float invN = 1.0f / (float)total;

    hipMemsetAsync(cnt, 0, sizeof(unsigned), stream);
    ssim_main<<<grid, 256, 0, stream>>>(x, y, w2d, part, cnt, out, nblk, invN);
}

// Round 4
// 253.490 us; speedup vs baseline: 2.2113x; 2.2113x over previous
//
#include <hip/hip_runtime.h>

// SSIM loss via separable 11-tap Gaussian, both conv passes on matrix cores
// (v_mfma_f32_16x16x32_f16). R14 = R13 geometry with the poison removed.
// R13's 9x regression was the fused reduction's cache-maintenance ops:
// __threadfence (device-scope -> buffer_wbl2) + acq_rel agent atomics
// (acquire -> cache invalidate) serialized ALL 6144 blocks' retirement
// (4% VALU, 1% HBM, FETCH unchanged). R14's rules: NO fences, NO acq/rel.
//  - Fused reduction, fence-free: block partial -> relaxed agent-scope
//    float atomicAdd (plain global_atomic_add_f32) -> s_waitcnt vmcnt(0)
//    -> relaxed counter fetch_add. Counter==nblk-1 implies all float adds
//    complete (each block's add is ack'd before its counter add issues).
//    Last block atomic-loads the accumulator, writes out. One kernel.
//  - B-operand register cache: each wave's 2-3 (xa,ya) pairs are loaded
//    ONCE before the chunk loop (R13 re-read them every chunk): -40KB/block
//    LDS reads. Static register names (runtime-indexed arrays -> scratch).
//  - Conflict-free tap table: tb[12][16] replicated; read addr
//    16*u + (lm ^ ((lg&1)<<3)) puts exactly 2 lanes/bank (b32 minimum).
//    Replaces the per-lane gsf gathers (the ~520 cyc/block conflict source).
// Geometry (from R13, harness-verified): x0=32bx-8 (48 staged cols),
// y0=64by-9 (80 rows); sx/sy 80x24 words col-pair f16 (b128 frags); phase B
// taps t=k-lm-3 shared by both col-tiles, bands {0,16,32,48,64}; hq
// column-major [2][32][40] (b64 stores / b128 reads, bank-balanced);
// phase C rpb=8*wv uniform, taps t=k-lm-4; 3-chunk quantity loop
// ({x,y},{xx,yy},{xy}) over 2-slot hq. All wave64 LDS patterns at the
// words/bank minimum. LDS 26.4KB -> 6 blocks/CU.

typedef __fp16 f16x8 __attribute__((ext_vector_type(8)));
typedef float f32x4 __attribute__((ext_vector_type(4)));
typedef unsigned u32x4 __attribute__((ext_vector_type(4)));

__device__ __forceinline__ unsigned pk2(float a, float b) {
    return __builtin_bit_cast(unsigned, __builtin_amdgcn_cvt_pkrtz(a, b));
}
__device__ __forceinline__ f32x4 mfma16(f16x8 a, f16x8 b, f32x4 c) {
    return __builtin_amdgcn_mfma_f32_16x16x32_f16(a, b, c, 0, 0, 0);
}

#define SXW 24   // staged words/row (48 f16 cols), rows 16B-aligned
#define HRP 40   // hq row-pairs per column (80 staged rows)

__global__ __launch_bounds__(256, 6) void ssim_main(
    const float* __restrict__ xg, const float* __restrict__ yg,
    const float* __restrict__ w2d, float* __restrict__ accg,
    unsigned* __restrict__ cnt, float* __restrict__ out,
    int nblk, float invN)
{
    __shared__ __align__(16) unsigned sx[80 * SXW];      // 7680 B
    __shared__ __align__(16) unsigned sy[80 * SXW];      // 7680 B
    __shared__ __align__(16) unsigned hq[2][32 * HRP];   // 10240 B
    __shared__ float tb[12 * 16];                        // 768 B tap table
    __shared__ float gsf[12];
    __shared__ float wred[4];
    __shared__ int isLast;

    const int tid = threadIdx.x;

    // 1D kernel = row sums of the 2D window (outer(g,g), sum 1).
    // gsf[11] = 0 sentinel.
    if (tid < 12) {
        float s = 0.0f;
        if (tid < 11) {
            #pragma unroll
            for (int j = 0; j < 11; ++j) s += w2d[tid * 11 + j];
        }
        gsf[tid] = s;
    }

    // XCD-aware bijective swizzle (nwg = 128*Z, %8==0).
    const int nwg = 128 * (int)gridDim.z;
    const int flat = (int)blockIdx.x + 16 * ((int)blockIdx.y + 8 * (int)blockIdx.z);
    const int swz = (flat & 7) * (nwg >> 3) + (flat >> 3);
    const int bx = swz & 15, by = (swz >> 4) & 7, bz = swz >> 7;

    const int x0 = bx * 32 - 8;   // mult of 4 -> float4-aligned
    const int y0 = by * 64 - 9;
    const size_t zoff = (size_t)bz * (512 * 512);
    const float* __restrict__ xp = xg + zoff;
    const float* __restrict__ yp = yg + zoff;

    // Phase A: stage 80 rows x 12 float4-groups, zero-padded at edges.
    const bool interior = (x0 >= 0) & (x0 + 47 < 512) & (y0 >= 0) & (y0 + 79 < 512);
    if (interior) {
        for (int it = tid; it < 80 * 12; it += 256) {
            const int r = it / 12, c4 = it - r * 12;
            const int o = (y0 + r) * 512 + x0 + 4 * c4;
            const float4 vx = *(const float4*)&xp[o];
            const float4 vy = *(const float4*)&yp[o];
            *(uint2*)&sx[2 * it] = make_uint2(pk2(vx.x, vx.y), pk2(vx.z, vx.w));
            *(uint2*)&sy[2 * it] = make_uint2(pk2(vy.x, vy.y), pk2(vy.z, vy.w));
        }
    } else {
        for (int it = tid; it < 80 * 12; it += 256) {
            const int r = it / 12, c4 = it - r * 12;
            const int gr = y0 + r, gc0 = x0 + 4 * c4;
            const bool rok = (unsigned)gr < 512u;
            float xv[4], yv[4];
            #pragma unroll
            for (int j = 0; j < 4; ++j) {
                const int gc = gc0 + j;
                const bool ok = rok & ((unsigned)gc < 512u);
                const int o = gr * 512 + gc;
                xv[j] = ok ? xp[o] : 0.f;
                yv[j] = ok ? yp[o] : 0.f;
            }
            *(uint2*)&sx[2 * it] = make_uint2(pk2(xv[0], xv[1]), pk2(xv[2], xv[3]));
            *(uint2*)&sy[2 * it] = make_uint2(pk2(yv[0], yv[1]), pk2(yv[2], yv[3]));
        }
    }
    __syncthreads();

    // Tap table build: tb[t][0..15] all hold tap t (f16-rounded, center-
    // corrected so the f16 tap sum is ~1; t=11 is the 0 sentinel). The
    // replication lets the fragment build below be bank-conflict-free.
    if (tid < 192) {
        const int t = tid >> 4;
        float ssum = 0.0f;
        #pragma unroll
        for (int k = 0; k < 11; ++k)
            if (k != 5) ssum += (float)(__fp16)gsf[k];
        const float ccf = (float)(__fp16)(1.0f - ssum);
        const float tv = (float)(__fp16)gsf[t];
        tb[tid] = (t == 5) ? ccf : tv;
    }
    __syncthreads();

    const int lane = tid & 63, wv = tid >> 6;
    const int lm = lane & 15, lg = lane >> 4;

    // Tap fragments (k = 8*lg + e):
    //  Phase B (B operand, both tiles): t = k - lm - 3
    //  Phase C (A operand, all waves):  t = k - lm - 4
    // Read addr 16*u + j with j = lm ^ ((lg&1)<<3): exactly 2 lanes/bank.
    f16x8 bt, afr;
    {
        const int j = lm ^ ((lg & 1) << 3);
        #pragma unroll
        for (int e = 0; e < 8; ++e) {
            const int k = 8 * lg + e;
            const unsigned t1 = (unsigned)(k - lm - 3);
            const unsigned t2 = (unsigned)(k - lm - 4);
            const unsigned u1 = t1 <= 11u ? t1 : 11u;
            const unsigned u2 = t2 <= 11u ? t2 : 11u;
            bt[e]  = (__fp16)tb[16 * u1 + j];
            afr[e] = (__fp16)tb[16 * u2 + j];
        }
    }

    // B-operand register cache: wave wv owns items {wv, wv+4, wv+8(wv<2)};
    // item i: band b=i>>1 (staged rows 16b..16b+15), col-tile tl=i&1.
    const bool v2 = (wv < 2);
    auto ldpair = [&](int i, f16x8& xa, f16x8& ya) {
        const int b = i >> 1, tl = i & 1;
        const int sbase = (16 * b + lm) * SXW + 8 * tl + 4 * lg;
        xa = __builtin_bit_cast(f16x8, *(const u32x4*)&sx[sbase]);
        ya = __builtin_bit_cast(f16x8, *(const u32x4*)&sy[sbase]);
    };
    f16x8 xa0, ya0, xa1, ya1, xa2, ya2;
    ldpair(wv,     xa0, ya0);
    ldpair(wv + 4, xa1, ya1);
    ldpair(v2 ? wv + 8 : wv, xa2, ya2);   // clamped read; store predicated

    f32x4 acc[2][5];
    #pragma unroll
    for (int ch = 0; ch < 2; ++ch)
        #pragma unroll
        for (int q = 0; q < 5; ++q)
            acc[ch][q] = (f32x4){0.f, 0.f, 0.f, 0.f};

    const int rpb = 8 * wv;   // hq rp base of the C-phase K window

    // Chunks over quantities: {x,y} -> {x*x,y*y} -> {x*y}, reusing hq[0..1].
    #pragma unroll
    for (int chunk = 0; chunk < 3; ++chunk) {
        auto bitem = [&](const f16x8& xa, const f16x8& ya, int i, bool valid) {
            if (!valid) return;                       // wave-uniform branch
            const int b = i >> 1, tl = i & 1;
            const f32x4 z4 = {0.f, 0.f, 0.f, 0.f};
            f32x4 d0 = z4, d1 = z4;
            if (chunk == 0)      { d0 = mfma16(xa, bt, z4);      d1 = mfma16(ya, bt, z4); }
            else if (chunk == 1) { d0 = mfma16(xa * xa, bt, z4); d1 = mfma16(ya * ya, bt, z4); }
            else                 { d0 = mfma16(xa * ya, bt, z4); }
            // D: col = lm (+16*tl), staged rows 16b+4lg+{0..3}
            //  -> rp = 8b+2lg, +1: contiguous in col-major hq -> ds_write_b64.
            const int ob = (16 * tl + lm) * HRP + 8 * b + 2 * lg;
            *(uint2*)&hq[0][ob] = make_uint2(pk2(d0[0], d0[1]), pk2(d0[2], d0[3]));
            if (chunk < 2)
                *(uint2*)&hq[1][ob] = make_uint2(pk2(d1[0], d1[1]), pk2(d1[2], d1[3]));
        };
        bitem(xa0, ya0, wv,     true);
        bitem(xa1, ya1, wv + 4, true);
        bitem(xa2, ya2, wv + 8, v2);
        __syncthreads();

        // Phase C: vertical conv as MFMA into the chunk's accumulators.
        #pragma unroll
        for (int ch = 0; ch < 2; ++ch) {
            const int cb = (16 * ch + lm) * HRP + rpb + 4 * lg;  // 16B aligned
            #pragma unroll
            for (int s = 0; s < 2; ++s) {
                if (chunk == 2 && s == 1) continue;
                const u32x4 w4 = *(const u32x4*)&hq[s][cb];
                acc[ch][2 * chunk + s] =
                    mfma16(afr, __builtin_bit_cast(f16x8, w4), acc[ch][2 * chunk + s]);
            }
        }
        if (chunk < 2) __syncthreads();   // hq reads done before next B rewrites
    }

    // SSIM epilogue: lane holds out col 16ch+lm, out rows 16wv+4lg+{0..3}.
    float lsum = 0.0f;
    const float C1 = 1e-4f, C2 = 9e-4f;
    #pragma unroll
    for (int ch = 0; ch < 2; ++ch) {
        #pragma unroll
        for (int r = 0; r < 4; ++r) {
            const float mx = acc[ch][0][r], my = acc[ch][1][r];
            const float exx = acc[ch][2][r], eyy = acc[ch][3][r];
            const float exy = acc[ch][4][r];
            const float mx2 = mx * mx, my2 = my * my, mxy = mx * my;
            const float vx = exx - mx2, vy = eyy - my2, vxy = exy - mxy;
            const float num = (2.0f * mxy + C1) * (2.0f * vxy + C2);
            const float den = (mx2 + my2 + C1) * (vx + vy + C2) + 1e-12f;
            lsum = fmaf(num, __builtin_amdgcn_rcpf(den), lsum);
        }
    }

    // Wave reduce -> cross-wave via LDS -> fence-free fused grid reduction.
    #pragma unroll
    for (int off = 32; off > 0; off >>= 1)
        lsum += __shfl_down(lsum, off, 64);
    if ((tid & 63) == 0) wred[tid >> 6] = lsum;
    __syncthreads();
    if (tid == 0) {
        const float total = wred[0] + wred[1] + wred[2] + wred[3];
        // Relaxed device-scope atomics only: NO fences, NO cache flushes.
        __hip_atomic_fetch_add(accg, total, __ATOMIC_RELAXED,
                               __HIP_MEMORY_SCOPE_AGENT);
        // Ensure our float add is ack'd at the coherence point before the
        // counter add issues (counter==nblk-1 then implies all adds done).
        asm volatile("s_waitcnt vmcnt(0)" ::: "memory");
        const unsigned old = __hip_atomic_fetch_add(cnt, 1u, __ATOMIC_RELAXED,
                                                    __HIP_MEMORY_SCOPE_AGENT);
        isLast = (old == (unsigned)(nblk - 1));
    }
    __syncthreads();
    if (isLast && tid == 0) {
        const float s = __hip_atomic_load(accg, __ATOMIC_RELAXED,
                                          __HIP_MEMORY_SCOPE_AGENT);
        out[0] = 1.0f - s * invN;
    }
}

extern "C" void kernel_launch(void* const* d_in, const int* in_sizes, int n_in,
                              void* d_out, int out_size, void* d_ws, size_t ws_size,
                              hipStream_t stream) {
    const float* x   = (const float*)d_in[0];
    const float* y   = (const float*)d_in[1];
    const float* w2d = (const float*)d_in[2];  // (3,1,11,11); channels identical
    float* out  = (float*)d_out;
    float* accg = (float*)d_ws;                         // [0,4): float sum
    unsigned* cnt = (unsigned*)((char*)d_ws + 4);       // [4,8): block counter

    const int H = 512, W = 512;
    const int total = in_sizes[0];              // 16*3*512*512
    const int Z = total / (H * W);              // 48

    dim3 grid(W / 32, H / 64, Z);               // 16 x 8 x 48 = 6144 blocks
    const int nblk = (W / 32) * (H / 64) * Z;
    const float invN = 1.0f / (float)total;

    hipMemsetAsync(d_ws, 0, 8, stream);
    ssim_main<<<grid, 256, 0, stream>>>(x, y, w2d, accg, cnt, out, nblk, invN);
}

// Round 5
// 144.904 us; speedup vs baseline: 3.8683x; 1.7494x over previous
//
#include <hip/hip_runtime.h>

// SSIM loss via separable 11-tap Gaussian, both conv passes on matrix cores
// (v_mfma_f32_16x16x32_f16). R15 = R14 compute body + R12's two-kernel
// reduction. History of the reduction (hard-won, do NOT re-fuse):
//  - R13: fence+acq_rel fused reduction -> 9x regression (device-scope
//    cache-maintenance ops serialize all 6144 blocks' retirement).
//  - R14: relaxed same-line atomics -> still 3x slow (6144 agent-scope RMWs
//    to ONE cacheline ping-pong across 8 XCDs, ~25ns each ~= 150us tail).
//  - R15 (= R6/R12 finding): plain per-block store + tiny reduce kernel.
// Compute body (verified R14, all wave64 LDS patterns at words/bank min):
//  - Geometry: x0=32bx-8 (48 staged cols), y0=64by-9 (80 rows); sx/sy
//    80x24 words col-pair f16; phase A = float4 -> cvt_pk -> ds_write_b64.
//  - Phase B: A-op = one ds_read_b128; taps t=k-lm-3 shared by both
//    col-tiles; bands {0,16,32,48,64}; B-operands register-cached ONCE
//    before the chunk loop (2-3 items/wave).
//  - hq column-major [2][32][40]: b64 stores / b128 reads, bank-balanced.
//  - Phase C: rpb=8*wv uniform, taps t=k-lm-4; 3-chunk quantity loop
//    ({x,y},{xx,yy},{xy}) over 2-slot hq.
//  - Conflict-reduced replicated tap table tb[12][16].
// LDS 26.6KB -> 6 blocks/CU. XCD-aware bijective block swizzle.

typedef __fp16 f16x8 __attribute__((ext_vector_type(8)));
typedef float f32x4 __attribute__((ext_vector_type(4)));
typedef unsigned u32x4 __attribute__((ext_vector_type(4)));

__device__ __forceinline__ unsigned pk2(float a, float b) {
    return __builtin_bit_cast(unsigned, __builtin_amdgcn_cvt_pkrtz(a, b));
}
__device__ __forceinline__ f32x4 mfma16(f16x8 a, f16x8 b, f32x4 c) {
    return __builtin_amdgcn_mfma_f32_16x16x32_f16(a, b, c, 0, 0, 0);
}

#define SXW 24   // staged words/row (48 f16 cols), rows 16B-aligned
#define HRP 40   // hq row-pairs per column (80 staged rows)

__global__ __launch_bounds__(256, 6) void ssim_main(
    const float* __restrict__ xg, const float* __restrict__ yg,
    const float* __restrict__ w2d, float* __restrict__ part)
{
    __shared__ __align__(16) unsigned sx[80 * SXW];      // 7680 B
    __shared__ __align__(16) unsigned sy[80 * SXW];      // 7680 B
    __shared__ __align__(16) unsigned hq[2][32 * HRP];   // 10240 B
    __shared__ float tb[12 * 16];                        // 768 B tap table
    __shared__ float gsf[12];
    __shared__ float wred[4];

    const int tid = threadIdx.x;

    // 1D kernel = row sums of the 2D window (outer(g,g), sum 1).
    // gsf[11] = 0 sentinel.
    if (tid < 12) {
        float s = 0.0f;
        if (tid < 11) {
            #pragma unroll
            for (int j = 0; j < 11; ++j) s += w2d[tid * 11 + j];
        }
        gsf[tid] = s;
    }

    // XCD-aware bijective swizzle (nwg = 128*Z, %8==0).
    const int nwg = 128 * (int)gridDim.z;
    const int flat = (int)blockIdx.x + 16 * ((int)blockIdx.y + 8 * (int)blockIdx.z);
    const int swz = (flat & 7) * (nwg >> 3) + (flat >> 3);
    const int bx = swz & 15, by = (swz >> 4) & 7, bz = swz >> 7;

    const int x0 = bx * 32 - 8;   // mult of 4 -> float4-aligned
    const int y0 = by * 64 - 9;
    const size_t zoff = (size_t)bz * (512 * 512);
    const float* __restrict__ xp = xg + zoff;
    const float* __restrict__ yp = yg + zoff;

    // Phase A: stage 80 rows x 12 float4-groups, zero-padded at edges.
    const bool interior = (x0 >= 0) & (x0 + 47 < 512) & (y0 >= 0) & (y0 + 79 < 512);
    if (interior) {
        for (int it = tid; it < 80 * 12; it += 256) {
            const int r = it / 12, c4 = it - r * 12;
            const int o = (y0 + r) * 512 + x0 + 4 * c4;
            const float4 vx = *(const float4*)&xp[o];
            const float4 vy = *(const float4*)&yp[o];
            *(uint2*)&sx[2 * it] = make_uint2(pk2(vx.x, vx.y), pk2(vx.z, vx.w));
            *(uint2*)&sy[2 * it] = make_uint2(pk2(vy.x, vy.y), pk2(vy.z, vy.w));
        }
    } else {
        for (int it = tid; it < 80 * 12; it += 256) {
            const int r = it / 12, c4 = it - r * 12;
            const int gr = y0 + r, gc0 = x0 + 4 * c4;
            const bool rok = (unsigned)gr < 512u;
            float xv[4], yv[4];
            #pragma unroll
            for (int j = 0; j < 4; ++j) {
                const int gc = gc0 + j;
                const bool ok = rok & ((unsigned)gc < 512u);
                const int o = gr * 512 + gc;
                xv[j] = ok ? xp[o] : 0.f;
                yv[j] = ok ? yp[o] : 0.f;
            }
            *(uint2*)&sx[2 * it] = make_uint2(pk2(xv[0], xv[1]), pk2(xv[2], xv[3]));
            *(uint2*)&sy[2 * it] = make_uint2(pk2(yv[0], yv[1]), pk2(yv[2], yv[3]));
        }
    }
    __syncthreads();

    // Tap table: tb[t][0..15] all hold tap t (f16-rounded, center-corrected
    // so the f16 tap sum ~= 1; t=11 is the 0 sentinel).
    if (tid < 192) {
        const int t = tid >> 4;
        float ssum = 0.0f;
        #pragma unroll
        for (int k = 0; k < 11; ++k)
            if (k != 5) ssum += (float)(__fp16)gsf[k];
        const float ccf = (float)(__fp16)(1.0f - ssum);
        const float tv = (float)(__fp16)gsf[t];
        tb[tid] = (t == 5) ? ccf : tv;
    }
    __syncthreads();

    const int lane = tid & 63, wv = tid >> 6;
    const int lm = lane & 15, lg = lane >> 4;

    // Tap fragments (k = 8*lg + e):
    //  Phase B (B operand, both tiles): t = k - lm - 3
    //  Phase C (A operand, all waves):  t = k - lm - 4
    f16x8 bt, afr;
    {
        const int j = lm ^ ((lg & 1) << 3);
        #pragma unroll
        for (int e = 0; e < 8; ++e) {
            const int k = 8 * lg + e;
            const unsigned t1 = (unsigned)(k - lm - 3);
            const unsigned t2 = (unsigned)(k - lm - 4);
            const unsigned u1 = t1 <= 11u ? t1 : 11u;
            const unsigned u2 = t2 <= 11u ? t2 : 11u;
            bt[e]  = (__fp16)tb[16 * u1 + j];
            afr[e] = (__fp16)tb[16 * u2 + j];
        }
    }

    // B-operand register cache: wave wv owns items {wv, wv+4, wv+8(wv<2)};
    // item i: band b=i>>1 (staged rows 16b..16b+15), col-tile tl=i&1.
    const bool v2 = (wv < 2);
    auto ldpair = [&](int i, f16x8& xa, f16x8& ya) {
        const int b = i >> 1, tl = i & 1;
        const int sbase = (16 * b + lm) * SXW + 8 * tl + 4 * lg;
        xa = __builtin_bit_cast(f16x8, *(const u32x4*)&sx[sbase]);
        ya = __builtin_bit_cast(f16x8, *(const u32x4*)&sy[sbase]);
    };
    f16x8 xa0, ya0, xa1, ya1, xa2, ya2;
    ldpair(wv,     xa0, ya0);
    ldpair(wv + 4, xa1, ya1);
    ldpair(v2 ? wv + 8 : wv, xa2, ya2);   // clamped read; store predicated

    f32x4 acc[2][5];
    #pragma unroll
    for (int ch = 0; ch < 2; ++ch)
        #pragma unroll
        for (int q = 0; q < 5; ++q)
            acc[ch][q] = (f32x4){0.f, 0.f, 0.f, 0.f};

    const int rpb = 8 * wv;   // hq rp base of the C-phase K window

    // Chunks over quantities: {x,y} -> {x*x,y*y} -> {x*y}, reusing hq[0..1].
    #pragma unroll
    for (int chunk = 0; chunk < 3; ++chunk) {
        auto bitem = [&](const f16x8& xa, const f16x8& ya, int i, bool valid) {
            if (!valid) return;                       // wave-uniform branch
            const int b = i >> 1, tl = i & 1;
            const f32x4 z4 = {0.f, 0.f, 0.f, 0.f};
            f32x4 d0 = z4, d1 = z4;
            if (chunk == 0)      { d0 = mfma16(xa, bt, z4);      d1 = mfma16(ya, bt, z4); }
            else if (chunk == 1) { d0 = mfma16(xa * xa, bt, z4); d1 = mfma16(ya * ya, bt, z4); }
            else                 { d0 = mfma16(xa * ya, bt, z4); }
            // D: col = lm (+16*tl), staged rows 16b+4lg+{0..3}
            //  -> rp = 8b+2lg, +1: contiguous in col-major hq -> ds_write_b64.
            const int ob = (16 * tl + lm) * HRP + 8 * b + 2 * lg;
            *(uint2*)&hq[0][ob] = make_uint2(pk2(d0[0], d0[1]), pk2(d0[2], d0[3]));
            if (chunk < 2)
                *(uint2*)&hq[1][ob] = make_uint2(pk2(d1[0], d1[1]), pk2(d1[2], d1[3]));
        };
        bitem(xa0, ya0, wv,     true);
        bitem(xa1, ya1, wv + 4, true);
        bitem(xa2, ya2, wv + 8, v2);
        __syncthreads();

        // Phase C: vertical conv as MFMA into the chunk's accumulators.
        #pragma unroll
        for (int ch = 0; ch < 2; ++ch) {
            const int cb = (16 * ch + lm) * HRP + rpb + 4 * lg;  // 16B aligned
            #pragma unroll
            for (int s = 0; s < 2; ++s) {
                if (chunk == 2 && s == 1) continue;
                const u32x4 w4 = *(const u32x4*)&hq[s][cb];
                acc[ch][2 * chunk + s] =
                    mfma16(afr, __builtin_bit_cast(f16x8, w4), acc[ch][2 * chunk + s]);
            }
        }
        if (chunk < 2) __syncthreads();   // hq reads done before next B rewrites
    }

    // SSIM epilogue: lane holds out col 16ch+lm, out rows 16wv+4lg+{0..3}.
    float lsum = 0.0f;
    const float C1 = 1e-4f, C2 = 9e-4f;
    #pragma unroll
    for (int ch = 0; ch < 2; ++ch) {
        #pragma unroll
        for (int r = 0; r < 4; ++r) {
            const float mx = acc[ch][0][r], my = acc[ch][1][r];
            const float exx = acc[ch][2][r], eyy = acc[ch][3][r];
            const float exy = acc[ch][4][r];
            const float mx2 = mx * mx, my2 = my * my, mxy = mx * my;
            const float vx = exx - mx2, vy = eyy - my2, vxy = exy - mxy;
            const float num = (2.0f * mxy + C1) * (2.0f * vxy + C2);
            const float den = (mx2 + my2 + C1) * (vx + vy + C2) + 1e-12f;
            lsum = fmaf(num, __builtin_amdgcn_rcpf(den), lsum);
        }
    }

    // Wave reduce -> cross-wave via LDS -> one plain store per block.
    #pragma unroll
    for (int off = 32; off > 0; off >>= 1)
        lsum += __shfl_down(lsum, off, 64);
    if ((tid & 63) == 0) wred[tid >> 6] = lsum;
    __syncthreads();
    if (tid == 0) part[swz] = wred[0] + wred[1] + wred[2] + wred[3];
}

__global__ __launch_bounds__(256) void ssim_reduce(
    const float* __restrict__ part, float* __restrict__ out,
    int n, float invN)
{
    __shared__ float wred[4];
    float s = 0.0f;
    for (int i = threadIdx.x; i < n; i += 256) s += part[i];
    #pragma unroll
    for (int off = 32; off > 0; off >>= 1)
        s += __shfl_down(s, off, 64);
    if ((threadIdx.x & 63) == 0) wred[threadIdx.x >> 6] = s;
    __syncthreads();
    if (threadIdx.x == 0)
        out[0] = 1.0f - (wred[0] + wred[1] + wred[2] + wred[3]) * invN;
}

extern "C" void kernel_launch(void* const* d_in, const int* in_sizes, int n_in,
                              void* d_out, int out_size, void* d_ws, size_t ws_size,
                              hipStream_t stream) {
    const float* x   = (const float*)d_in[0];
    const float* y   = (const float*)d_in[1];
    const float* w2d = (const float*)d_in[2];  // (3,1,11,11); channels identical
    float* out  = (float*)d_out;
    float* part = (float*)d_ws;                // 6144 floats = 24 KB

    const int H = 512, W = 512;
    const int total = in_sizes[0];              // 16*3*512*512
    const int Z = total / (H * W);              // 48

    dim3 grid(W / 32, H / 64, Z);               // 16 x 8 x 48 = 6144 blocks
    const int nblk = (W / 32) * (H / 64) * Z;
    ssim_main<<<grid, 256, 0, stream>>>(x, y, w2d, part);

    const float invN = 1.0f / (float)total;
    ssim_reduce<<<1, 256, 0, stream>>>(part, out, nblk, invN);
}